// Round 1
// baseline (197.503 us; speedup 1.0000x reference)
//
#include <hip/hip_runtime.h>

#define B_ 4
#define C_ 128
#define N_ 8192
#define K_ 16

// workspace layout (in floats)
#define WS_LOCAL 0ULL
#define WS_EDGE  (4ULL * 8192 * 128)          // 4,194,304
#define WS_PART  (8ULL * 8192 * 128)          // 8,388,608
#define NBLK_STATS 1024
#define WS_COEF  (WS_PART + 512ULL * NBLK_STATS)
#define WS_WT1   (WS_COEF + 512ULL)
#define WS_WT2   (WS_WT1 + 16384ULL)
#define WS_TOTAL (WS_WT2 + 16384ULL)

// K0: transpose W (O,C) -> Wt (C,O) so GEMM weight loads are coalesced.
__global__ __launch_bounds__(128) void k_transpose(const float* __restrict__ w1,
    const float* __restrict__ w2, float* __restrict__ wt1, float* __restrict__ wt2) {
  int c = blockIdx.x;
  int o = threadIdx.x;
  if (blockIdx.y == 0) wt1[c * 128 + o] = w1[o * 128 + c];
  else                 wt2[c * 128 + o] = w2[o * 128 + c];
}

// K1: local[b][n][o] = sum_c W1[o][c] * feat[b][c][n]; same for edge/W2.
// Block: 32 n x 128 o, 256 threads, per-thread 4n x 4o x 2 matrices.
__global__ __launch_bounds__(256) void k_gemm(const float* __restrict__ feat,
    const float* __restrict__ wt1, const float* __restrict__ wt2,
    float* __restrict__ localW, float* __restrict__ edgeW) {
  __shared__ float fs[32][32];     // [c][n]
  __shared__ float w1s[32][128];   // [c][o]
  __shared__ float w2s[32][128];
  const int t = threadIdx.x;
  const int b = blockIdx.x >> 8;
  const int nblk = (blockIdx.x & 255) << 5;
  const int ot = t & 31;   // o-tile: 4 o each
  const int nt = t >> 5;   // n-tile: 4 n each (8 tiles)
  float acc1[4][4] = {{0.f}};
  float acc2[4][4] = {{0.f}};
  const float* fb = feat + (size_t)b * C_ * N_;
  for (int c0 = 0; c0 < C_; c0 += 32) {
    {
      int c = t >> 3, n4 = (t & 7) << 2;
      *(float4*)&fs[c][n4] = *(const float4*)&fb[(size_t)(c0 + c) * N_ + nblk + n4];
    }
#pragma unroll
    for (int i = 0; i < 4; i++) {
      int c = (i << 3) + nt, o4 = ot << 2;
      *(float4*)&w1s[c][o4] = *(const float4*)&wt1[(c0 + c) * 128 + o4];
      *(float4*)&w2s[c][o4] = *(const float4*)&wt2[(c0 + c) * 128 + o4];
    }
    __syncthreads();
#pragma unroll 8
    for (int cc = 0; cc < 32; cc++) {
      float fv[4], w1v[4], w2v[4];
      *(float4*)fv  = *(float4*)&fs[cc][nt << 2];
      *(float4*)w1v = *(float4*)&w1s[cc][ot << 2];
      *(float4*)w2v = *(float4*)&w2s[cc][ot << 2];
#pragma unroll
      for (int i = 0; i < 4; i++)
#pragma unroll
        for (int j = 0; j < 4; j++) {
          acc1[i][j] = fmaf(fv[i], w1v[j], acc1[i][j]);
          acc2[i][j] = fmaf(fv[i], w2v[j], acc2[i][j]);
        }
    }
    __syncthreads();
  }
#pragma unroll
  for (int i = 0; i < 4; i++) {
    int n = nblk + (nt << 2) + i;
    size_t base = ((size_t)b * N_ + n) * 128 + (ot << 2);
    *(float4*)&localW[base] = make_float4(acc1[i][0], acc1[i][1], acc1[i][2], acc1[i][3]);
    *(float4*)&edgeW[base]  = make_float4(acc2[i][0], acc2[i][1], acc2[i][2], acc2[i][3]);
  }
}

// K2: per-block partial sums/sumsq for the 256 BN channels.
// Block: (b, 32 n). red[c]=sum, red[256+c]=sumsq. c<128: local; c>=128: edge[idx]-local.
__global__ __launch_bounds__(256) void k_stats(const float* __restrict__ localW,
    const float* __restrict__ edgeW, const int* __restrict__ knn,
    float* __restrict__ partials) {
  __shared__ int knn_s[512];
  __shared__ float red[512];
  const int t = threadIdx.x;
  const int b = blockIdx.x >> 8;
  const int n0 = (blockIdx.x & 255) << 5;
  red[t] = 0.f; red[t + 256] = 0.f;
  const int* kb = knn + ((size_t)b * N_ + n0) * K_;
  knn_s[t] = kb[t];
  knn_s[t + 256] = kb[t + 256];
  __syncthreads();
  const int g = t >> 5;            // 8 groups over n
  const int o4 = (t & 31) << 2;    // 4 channels per lane
  float sl[4] = {0,0,0,0}, sl2[4] = {0,0,0,0}, sd[4] = {0,0,0,0}, sd2[4] = {0,0,0,0};
  const float* lb = localW + (size_t)b * N_ * 128;
  const float* eb = edgeW + (size_t)b * N_ * 128;
  for (int i = 0; i < 4; i++) {
    int nl = g + (i << 3);
    float lv[4];
    *(float4*)lv = *(const float4*)&lb[(size_t)(n0 + nl) * 128 + o4];
#pragma unroll
    for (int j = 0; j < 4; j++) { sl[j] += lv[j]; sl2[j] = fmaf(lv[j], lv[j], sl2[j]); }
#pragma unroll
    for (int k = 0; k < K_; k++) {
      int idx = knn_s[(nl << 4) + k];
      float ev[4];
      *(float4*)ev = *(const float4*)&eb[(size_t)idx * 128 + o4];
#pragma unroll
      for (int j = 0; j < 4; j++) {
        float d = ev[j] - lv[j];
        sd[j] += d; sd2[j] = fmaf(d, d, sd2[j]);
      }
    }
  }
#pragma unroll
  for (int j = 0; j < 4; j++) {
    atomicAdd(&red[o4 + j], sl[j]);
    atomicAdd(&red[256 + o4 + j], sl2[j]);
    atomicAdd(&red[128 + o4 + j], sd[j]);
    atomicAdd(&red[384 + o4 + j], sd2[j]);
  }
  __syncthreads();
  float* pb = partials + (size_t)blockIdx.x * 512;
  pb[t] = red[t];
  pb[t + 256] = red[t + 256];
}

// K3: reduce partials -> per-channel affine coefs: y = a*x + b (folds mean/var/gamma/beta).
__global__ __launch_bounds__(256) void k_coef(const float* __restrict__ partials,
    const float* __restrict__ gamma, const float* __restrict__ beta,
    float* __restrict__ coef) {
  const int c = blockIdx.x;  // 0..255
  const int t = threadIdx.x;
  float s = 0.f, q = 0.f;
  for (int j = t; j < NBLK_STATS; j += 256) {
    s += partials[(size_t)j * 512 + c];
    q += partials[(size_t)j * 512 + 256 + c];
  }
#pragma unroll
  for (int off = 32; off > 0; off >>= 1) {
    s += __shfl_down(s, off);
    q += __shfl_down(q, off);
  }
  __shared__ float rs[4], rq[4];
  int w = t >> 6;
  if ((t & 63) == 0) { rs[w] = s; rq[w] = q; }
  __syncthreads();
  if (t == 0) {
    float S = rs[0] + rs[1] + rs[2] + rs[3];
    float Q = rq[0] + rq[1] + rq[2] + rq[3];
    float cnt = (c < 128) ? (float)(B_ * N_) : (float)(B_ * N_ * K_);
    float mean = S / cnt;
    float var = fmaxf(Q / cnt - mean * mean, 0.f);
    float a = gamma[c] * rsqrtf(var + 1e-5f);
    coef[c] = a;
    coef[256 + c] = beta[c] - mean * a;
  }
}

// K4: out[b][c][n]. c<128: relu(a*local+b). c>=128: mean_k relu(a*(edge[idx]-local)+b).
// Computed o-major (contiguous gathers), transposed via padded LDS tile for coalesced writes.
__global__ __launch_bounds__(256) void k_out(const float* __restrict__ localW,
    const float* __restrict__ edgeW, const int* __restrict__ knn,
    const float* __restrict__ coef, float* __restrict__ out) {
  __shared__ float tile[256][33];   // stride 33: conflict-light both directions
  __shared__ int knn_s[512];
  __shared__ float ca[256], cb[256];
  const int t = threadIdx.x;
  const int b = blockIdx.x >> 8;
  const int n0 = (blockIdx.x & 255) << 5;
  const int* kb = knn + ((size_t)b * N_ + n0) * K_;
  knn_s[t] = kb[t];
  knn_s[t + 256] = kb[t + 256];
  ca[t] = coef[t];
  cb[t] = coef[256 + t];
  __syncthreads();
  const int g = t >> 5;
  const int o4 = (t & 31) << 2;
  const float* lb = localW + (size_t)b * N_ * 128;
  const float* eb = edgeW + (size_t)b * N_ * 128;
  for (int i = 0; i < 4; i++) {
    int nl = g + (i << 3);
    float lv[4];
    *(float4*)lv = *(const float4*)&lb[(size_t)(n0 + nl) * 128 + o4];
    float acc[4] = {0,0,0,0};
#pragma unroll
    for (int k = 0; k < K_; k++) {
      int idx = knn_s[(nl << 4) + k];
      float ev[4];
      *(float4*)ev = *(const float4*)&eb[(size_t)idx * 128 + o4];
#pragma unroll
      for (int j = 0; j < 4; j++) {
        float v = fmaf(ev[j] - lv[j], ca[128 + o4 + j], cb[128 + o4 + j]);
        acc[j] += fmaxf(v, 0.f);
      }
    }
#pragma unroll
    for (int j = 0; j < 4; j++) {
      tile[o4 + j][nl] = fmaxf(fmaf(lv[j], ca[o4 + j], cb[o4 + j]), 0.f);
      tile[128 + o4 + j][nl] = acc[j] * 0.0625f;
    }
  }
  __syncthreads();
  const int cr = t >> 3;
  const int n4 = (t & 7) << 2;
  float* ob = out + (size_t)b * 256 * N_;
#pragma unroll
  for (int p = 0; p < 8; p++) {
    int c = (p << 5) + cr;
    float4 v = make_float4(tile[c][n4], tile[c][n4 + 1], tile[c][n4 + 2], tile[c][n4 + 3]);
    *(float4*)&ob[(size_t)c * N_ + n0 + n4] = v;
  }
}

extern "C" void kernel_launch(void* const* d_in, const int* in_sizes, int n_in,
                              void* d_out, int out_size, void* d_ws, size_t ws_size,
                              hipStream_t stream) {
  const float* feat  = (const float*)d_in[0];
  const int*   knn   = (const int*)d_in[1];
  const float* w1    = (const float*)d_in[2];
  const float* w2    = (const float*)d_in[3];
  const float* gamma = (const float*)d_in[4];
  const float* beta  = (const float*)d_in[5];
  float* ws = (float*)d_ws;
  if (ws_size < WS_TOTAL * sizeof(float)) return;  // fail visibly, don't corrupt
  float* localW   = ws + WS_LOCAL;
  float* edgeW    = ws + WS_EDGE;
  float* partials = ws + WS_PART;
  float* coef     = ws + WS_COEF;
  float* wt1      = ws + WS_WT1;
  float* wt2      = ws + WS_WT2;
  float* outp = (float*)d_out;

  hipLaunchKernelGGL(k_transpose, dim3(128, 2), dim3(128), 0, stream, w1, w2, wt1, wt2);
  hipLaunchKernelGGL(k_gemm, dim3(1024), dim3(256), 0, stream, feat, wt1, wt2, localW, edgeW);
  hipLaunchKernelGGL(k_stats, dim3(1024), dim3(256), 0, stream, localW, edgeW, knn, partials);
  hipLaunchKernelGGL(k_coef, dim3(256), dim3(256), 0, stream, partials, gamma, beta, coef);
  hipLaunchKernelGGL(k_out, dim3(1024), dim3(256), 0, stream, localW, edgeW, knn, coef, outp);
}

// Round 2
// 174.537 us; speedup vs baseline: 1.1316x; 1.1316x over previous
//
#include <hip/hip_runtime.h>
#include <hip/hip_bf16.h>

#define B_ 4
#define C_ 128
#define N_ 8192
#define K_ 16
#define NBLK_STATS 2048

typedef __attribute__((ext_vector_type(8))) short short8;
typedef __attribute__((ext_vector_type(4))) float floatx4;

static __device__ __forceinline__ unsigned short f2b(float x) {
  return __builtin_bit_cast(unsigned short, __float2bfloat16(x));
}
static __device__ __forceinline__ float b2f(unsigned short u) {
  return __builtin_bit_cast(float, ((unsigned int)u) << 16);
}

// workspace byte offsets
#define OFF_LOCAL 0ULL
#define OFF_EDGE  8388608ULL
#define OFF_WBF1  16777216ULL
#define OFF_WBF2  16809984ULL
#define OFF_PART  16842752ULL
#define OFF_COEF  21037056ULL
#define WS_BYTES  21039104ULL

// K0: cast W1,W2 (O=128,C=128 fp32, [o][c]) -> bf16, same layout.
__global__ __launch_bounds__(256) void k_prep(const float* __restrict__ w1,
    const float* __restrict__ w2, unsigned short* __restrict__ wbf1,
    unsigned short* __restrict__ wbf2) {
  int i = blockIdx.x * 256 + threadIdx.x;   // 64 blocks -> 16384
  wbf1[i] = f2b(w1[i]);
  wbf2[i] = f2b(w2[i]);
}

// K1: MFMA dual-GEMM. D[o][n] = W . feat  (per batch), stored (b,n,o) bf16.
// Block: 64 n, 4 waves. Wave wv owns n-tile wv (16 n), loops 8 o-tiles x 4 k-steps.
// A = W[o][c] (global, L2-resident, already A-fragment layout).
// B = feat[c][n] staged bf16 in LDS (natural layout, already B-fragment layout).
// Output transposed through LDS -> coalesced (n,o)-major bf16 stores.
__global__ __launch_bounds__(256) void k_gemm(const float* __restrict__ feat,
    const unsigned short* __restrict__ wbf1, const unsigned short* __restrict__ wbf2,
    unsigned short* __restrict__ localB, unsigned short* __restrict__ edgeB) {
  __shared__ __align__(16) unsigned short lds_u[128 * 68];  // ldsB[c][68] == ldsO[n][136]
  const int t = threadIdx.x;
  const int b = blockIdx.x >> 7;
  const int n0 = (blockIdx.x & 127) << 6;
  const float* fb = feat + (size_t)b * C_ * N_;

  // stage feat tile (128 c x 64 n) fp32 -> bf16, natural [c][n] layout
#pragma unroll
  for (int i = 0; i < 8; i++) {
    int c = i * 16 + (t >> 4);
    int n4 = (t & 15) << 2;
    float4 f = *(const float4*)&fb[(size_t)c * N_ + n0 + n4];
    ushort4 u = make_ushort4(f2b(f.x), f2b(f.y), f2b(f.z), f2b(f.w));
    *(ushort4*)&lds_u[c * 68 + n4] = u;
  }
  __syncthreads();

  const int lane = t & 63, wv = t >> 6, l15 = lane & 15, q = lane >> 4;
  // B-fragments: lane holds B[k=q*8+j][n=wv*16+l15]; shared across o-tiles & both gemms
  short8 bfrag[4];
#pragma unroll
  for (int ks = 0; ks < 4; ks++)
#pragma unroll
    for (int j = 0; j < 8; j++)
      bfrag[ks][j] = (short)lds_u[(ks * 32 + q * 8 + j) * 68 + wv * 16 + l15];
  __syncthreads();  // all LDS reads done before reuse as output tile

#pragma unroll 1
  for (int g = 0; g < 2; g++) {
    const unsigned short* Wg = g ? wbf2 : wbf1;
    floatx4 acc[8];
#pragma unroll
    for (int mt = 0; mt < 8; mt++) acc[mt] = (floatx4){0.f, 0.f, 0.f, 0.f};
#pragma unroll
    for (int mt = 0; mt < 8; mt++)
#pragma unroll
      for (int ks = 0; ks < 4; ks++) {
        short8 af = *(const short8*)(Wg + (size_t)(mt * 16 + l15) * 128 + ks * 32 + q * 8);
        acc[mt] = __builtin_amdgcn_mfma_f32_16x16x32_bf16(af, bfrag[ks], acc[mt], 0, 0, 0);
      }
    // D[row=o: q*4+r within tile][col=n: l15] -> ldsO[n][o], r contiguous in o
#pragma unroll
    for (int mt = 0; mt < 8; mt++) {
      ushort4 u = make_ushort4(f2b(acc[mt][0]), f2b(acc[mt][1]), f2b(acc[mt][2]), f2b(acc[mt][3]));
      *(ushort4*)&lds_u[(wv * 16 + l15) * 136 + mt * 16 + q * 4] = u;
    }
    __syncthreads();
    unsigned short* dst = (g ? edgeB : localB) + ((size_t)b * N_ + n0) * 128;
#pragma unroll
    for (int i = 0; i < 4; i++) {
      int ng = i * 16 + (t >> 4);
      float4 v = *(float4*)&lds_u[ng * 136 + (t & 15) * 8];
      *(float4*)&dst[(size_t)ng * 128 + (t & 15) * 8] = v;
    }
    __syncthreads();
  }
}

// K2: per-block partial sum/sumsq for 256 BN channels; 16 n per block.
__global__ __launch_bounds__(256) void k_stats(const unsigned short* __restrict__ localB,
    const unsigned short* __restrict__ edgeB, const int* __restrict__ knn,
    float* __restrict__ partials) {
  __shared__ int knn_s[256];
  __shared__ float red[512];
  const int t = threadIdx.x;
  const int b = blockIdx.x >> 9;
  const int n0 = (blockIdx.x & 511) << 4;
  red[t] = 0.f; red[t + 256] = 0.f;
  knn_s[t] = knn[((size_t)b * N_ + n0) * K_ + t];
  __syncthreads();
  const int g = t >> 5;
  const int o4 = (t & 31) << 2;
  float sl[4] = {0,0,0,0}, sl2[4] = {0,0,0,0}, sd[4] = {0,0,0,0}, sd2[4] = {0,0,0,0};
  const unsigned short* lb = localB + (size_t)b * N_ * 128;
  const unsigned short* eb = edgeB + (size_t)b * N_ * 128;
#pragma unroll
  for (int i = 0; i < 2; i++) {
    int nl = g + (i << 3);
    ushort4 lu = *(const ushort4*)&lb[(size_t)(n0 + nl) * 128 + o4];
    float lv[4] = {b2f(lu.x), b2f(lu.y), b2f(lu.z), b2f(lu.w)};
#pragma unroll
    for (int j = 0; j < 4; j++) { sl[j] += lv[j]; sl2[j] = fmaf(lv[j], lv[j], sl2[j]); }
#pragma unroll
    for (int k = 0; k < K_; k++) {
      int idx = knn_s[(nl << 4) + k];
      ushort4 eu = *(const ushort4*)&eb[(size_t)idx * 128 + o4];
      float ev[4] = {b2f(eu.x), b2f(eu.y), b2f(eu.z), b2f(eu.w)};
#pragma unroll
      for (int j = 0; j < 4; j++) {
        float d = ev[j] - lv[j];
        sd[j] += d; sd2[j] = fmaf(d, d, sd2[j]);
      }
    }
  }
#pragma unroll
  for (int j = 0; j < 4; j++) {
    atomicAdd(&red[o4 + j], sl[j]);
    atomicAdd(&red[128 + o4 + j], sd[j]);
    atomicAdd(&red[256 + o4 + j], sl2[j]);
    atomicAdd(&red[384 + o4 + j], sd2[j]);
  }
  __syncthreads();
  float* pb = partials + (size_t)blockIdx.x * 512;
  pb[t] = red[t];
  pb[t + 256] = red[t + 256];
}

// K3: reduce partials -> per-channel affine coefs y = a*x + b.
__global__ __launch_bounds__(256) void k_coef(const float* __restrict__ partials,
    const float* __restrict__ gamma, const float* __restrict__ beta,
    float* __restrict__ coef) {
  const int c = blockIdx.x;
  const int t = threadIdx.x;
  float s = 0.f, q = 0.f;
  for (int j = t; j < NBLK_STATS; j += 256) {
    s += partials[(size_t)j * 512 + c];
    q += partials[(size_t)j * 512 + 256 + c];
  }
#pragma unroll
  for (int off = 32; off > 0; off >>= 1) {
    s += __shfl_down(s, off);
    q += __shfl_down(q, off);
  }
  __shared__ float rs[4], rq[4];
  int w = t >> 6;
  if ((t & 63) == 0) { rs[w] = s; rq[w] = q; }
  __syncthreads();
  if (t == 0) {
    float S = rs[0] + rs[1] + rs[2] + rs[3];
    float Q = rq[0] + rq[1] + rq[2] + rq[3];
    float cnt = (c < 128) ? (float)(B_ * N_) : (float)(B_ * N_ * K_);
    float mean = S / cnt;
    float var = fmaxf(Q / cnt - mean * mean, 0.f);
    float a = gamma[c] * rsqrtf(var + 1e-5f);
    coef[c] = a;
    coef[256 + c] = beta[c] - mean * a;
  }
}

// K4: out[b][c][n] fp32. c<128: relu(a*local+b). c>=128: mean_k relu(a*(edge[idx]-local)+b).
__global__ __launch_bounds__(256) void k_out(const unsigned short* __restrict__ localB,
    const unsigned short* __restrict__ edgeB, const int* __restrict__ knn,
    const float* __restrict__ coef, float* __restrict__ out) {
  __shared__ float tile[256][33];
  __shared__ int knn_s[512];
  __shared__ float ca[256], cb[256];
  const int t = threadIdx.x;
  const int b = blockIdx.x >> 8;
  const int n0 = (blockIdx.x & 255) << 5;
  const int* kb = knn + ((size_t)b * N_ + n0) * K_;
  knn_s[t] = kb[t];
  knn_s[t + 256] = kb[t + 256];
  ca[t] = coef[t];
  cb[t] = coef[256 + t];
  __syncthreads();
  const int g = t >> 5;
  const int o4 = (t & 31) << 2;
  const unsigned short* lb = localB + (size_t)b * N_ * 128;
  const unsigned short* eb = edgeB + (size_t)b * N_ * 128;
#pragma unroll
  for (int i = 0; i < 4; i++) {
    int nl = g + (i << 3);
    ushort4 lu = *(const ushort4*)&lb[(size_t)(n0 + nl) * 128 + o4];
    float lv[4] = {b2f(lu.x), b2f(lu.y), b2f(lu.z), b2f(lu.w)};
    float acc[4] = {0,0,0,0};
#pragma unroll
    for (int k = 0; k < K_; k++) {
      int idx = knn_s[(nl << 4) + k];
      ushort4 eu = *(const ushort4*)&eb[(size_t)idx * 128 + o4];
#pragma unroll
      for (int j = 0; j < 4; j++) {
        float v = fmaf(b2f(((const unsigned short*)&eu)[j]) - lv[j],
                       ca[128 + o4 + j], cb[128 + o4 + j]);
        acc[j] += fmaxf(v, 0.f);
      }
    }
#pragma unroll
    for (int j = 0; j < 4; j++) {
      tile[o4 + j][nl] = fmaxf(fmaf(lv[j], ca[o4 + j], cb[o4 + j]), 0.f);
      tile[128 + o4 + j][nl] = acc[j] * 0.0625f;
    }
  }
  __syncthreads();
  const int cr = t >> 3;
  const int n4 = (t & 7) << 2;
  float* ob = out + (size_t)b * 256 * N_;
#pragma unroll
  for (int p = 0; p < 8; p++) {
    int c = (p << 5) + cr;
    float4 v = make_float4(tile[c][n4], tile[c][n4 + 1], tile[c][n4 + 2], tile[c][n4 + 3]);
    *(float4*)&ob[(size_t)c * N_ + n0 + n4] = v;
  }
}

extern "C" void kernel_launch(void* const* d_in, const int* in_sizes, int n_in,
                              void* d_out, int out_size, void* d_ws, size_t ws_size,
                              hipStream_t stream) {
  const float* feat  = (const float*)d_in[0];
  const int*   knn   = (const int*)d_in[1];
  const float* w1    = (const float*)d_in[2];
  const float* w2    = (const float*)d_in[3];
  const float* gamma = (const float*)d_in[4];
  const float* beta  = (const float*)d_in[5];
  if (ws_size < WS_BYTES) return;
  unsigned char* ws = (unsigned char*)d_ws;
  unsigned short* localB = (unsigned short*)(ws + OFF_LOCAL);
  unsigned short* edgeB  = (unsigned short*)(ws + OFF_EDGE);
  unsigned short* wbf1   = (unsigned short*)(ws + OFF_WBF1);
  unsigned short* wbf2   = (unsigned short*)(ws + OFF_WBF2);
  float* partials        = (float*)(ws + OFF_PART);
  float* coef            = (float*)(ws + OFF_COEF);
  float* outp = (float*)d_out;

  hipLaunchKernelGGL(k_prep, dim3(64), dim3(256), 0, stream, w1, w2, wbf1, wbf2);
  hipLaunchKernelGGL(k_gemm, dim3(512), dim3(256), 0, stream, feat, wbf1, wbf2, localB, edgeB);
  hipLaunchKernelGGL(k_stats, dim3(2048), dim3(256), 0, stream, localB, edgeB, knn, partials);
  hipLaunchKernelGGL(k_coef, dim3(256), dim3(256), 0, stream, partials, gamma, beta, coef);
  hipLaunchKernelGGL(k_out, dim3(1024), dim3(256), 0, stream, localB, edgeB, knn, coef, outp);
}

// Round 3
// 159.192 us; speedup vs baseline: 1.2407x; 1.0964x over previous
//
#include <hip/hip_runtime.h>
#include <hip/hip_bf16.h>

#define B_ 4
#define C_ 128
#define N_ 8192
#define K_ 16
#define NBLK_STATS 2048

typedef __attribute__((ext_vector_type(8))) short short8;
typedef __attribute__((ext_vector_type(4))) float floatx4;

static __device__ __forceinline__ unsigned short f2b(float x) {
  return __builtin_bit_cast(unsigned short, __float2bfloat16(x));
}
// unpack 8 bf16 (uint4) -> 8 floats. low short of each word first.
static __device__ __forceinline__ void unpack8(uint4 u, float* f) {
  const unsigned* w = (const unsigned*)&u;
#pragma unroll
  for (int i = 0; i < 4; i++) {
    f[2 * i]     = __builtin_bit_cast(float, w[i] << 16);
    f[2 * i + 1] = __builtin_bit_cast(float, w[i] & 0xffff0000u);
  }
}

// workspace byte offsets
#define OFF_LOCAL 0ULL
#define OFF_EDGE  8388608ULL
#define OFF_WBF1  16777216ULL
#define OFF_WBF2  16809984ULL
#define OFF_PART  16842752ULL
#define OFF_COEF  21037056ULL
#define WS_BYTES  21039104ULL

// K0: cast W1,W2 -> bf16, same [o][c] layout.
__global__ __launch_bounds__(256) void k_prep(const float* __restrict__ w1,
    const float* __restrict__ w2, unsigned short* __restrict__ wbf1,
    unsigned short* __restrict__ wbf2) {
  int i = blockIdx.x * 256 + threadIdx.x;
  wbf1[i] = f2b(w1[i]);
  wbf2[i] = f2b(w2[i]);
}

// K1: MFMA dual-GEMM, output (b,n,o) bf16. Same verified fragment logic as R2;
// inner loop reordered: batch 8 independent af loads, then 8 independent MFMAs.
__global__ __launch_bounds__(256) void k_gemm(const float* __restrict__ feat,
    const unsigned short* __restrict__ wbf1, const unsigned short* __restrict__ wbf2,
    unsigned short* __restrict__ localB, unsigned short* __restrict__ edgeB) {
  __shared__ __align__(16) unsigned short lds_u[128 * 68];
  const int t = threadIdx.x;
  const int b = blockIdx.x >> 7;
  const int n0 = (blockIdx.x & 127) << 6;
  const float* fb = feat + (size_t)b * C_ * N_;
#pragma unroll
  for (int i = 0; i < 8; i++) {
    int c = i * 16 + (t >> 4);
    int n4 = (t & 15) << 2;
    float4 f = *(const float4*)&fb[(size_t)c * N_ + n0 + n4];
    ushort4 u = make_ushort4(f2b(f.x), f2b(f.y), f2b(f.z), f2b(f.w));
    *(ushort4*)&lds_u[c * 68 + n4] = u;
  }
  __syncthreads();
  const int lane = t & 63, wv = t >> 6, l15 = lane & 15, q = lane >> 4;
  short8 bfrag[4];
#pragma unroll
  for (int ks = 0; ks < 4; ks++)
#pragma unroll
    for (int j = 0; j < 8; j++)
      bfrag[ks][j] = (short)lds_u[(ks * 32 + q * 8 + j) * 68 + wv * 16 + l15];
  __syncthreads();

#pragma unroll 1
  for (int g = 0; g < 2; g++) {
    const unsigned short* Wg = g ? wbf2 : wbf1;
    floatx4 acc[8];
#pragma unroll
    for (int mt = 0; mt < 8; mt++) acc[mt] = (floatx4){0.f, 0.f, 0.f, 0.f};
#pragma unroll
    for (int ks = 0; ks < 4; ks++) {
      short8 af[8];
#pragma unroll
      for (int mt = 0; mt < 8; mt++)
        af[mt] = *(const short8*)(Wg + (size_t)(mt * 16 + l15) * 128 + ks * 32 + q * 8);
#pragma unroll
      for (int mt = 0; mt < 8; mt++)
        acc[mt] = __builtin_amdgcn_mfma_f32_16x16x32_bf16(af[mt], bfrag[ks], acc[mt], 0, 0, 0);
    }
#pragma unroll
    for (int mt = 0; mt < 8; mt++) {
      ushort4 u = make_ushort4(f2b(acc[mt][0]), f2b(acc[mt][1]), f2b(acc[mt][2]), f2b(acc[mt][3]));
      *(ushort4*)&lds_u[(wv * 16 + l15) * 136 + mt * 16 + q * 4] = u;
    }
    __syncthreads();
    unsigned short* dst = (g ? edgeB : localB) + ((size_t)b * N_ + n0) * 128;
#pragma unroll
    for (int i = 0; i < 4; i++) {
      int ng = i * 16 + (t >> 4);
      float4 v = *(float4*)&lds_u[ng * 136 + (t & 15) * 8];
      *(float4*)&dst[(size_t)ng * 128 + (t & 15) * 8] = v;
    }
    __syncthreads();
  }
}

// K2: stats. 16 n/block; thread = (slot n, 8-channel octet). Buffered 16B gathers.
__global__ __launch_bounds__(256, 4) void k_stats(const unsigned short* __restrict__ localB,
    const unsigned short* __restrict__ edgeB, const int* __restrict__ knn,
    float* __restrict__ partials) {
  __shared__ int knn_s[256];
  __shared__ float red[512];
  const int t = threadIdx.x;
  const int b = blockIdx.x >> 9;
  const int n0 = (blockIdx.x & 511) << 4;
  red[t] = 0.f; red[t + 256] = 0.f;
  knn_s[t] = knn[((size_t)b * N_ + n0) * K_ + t];
  __syncthreads();
  const int slot = t >> 4;          // n = n0 + slot
  const int co = t & 15;            // channels co*8 .. co*8+7
  const unsigned short* lb = localB + (size_t)b * N_ * 128;
  const unsigned short* eb = edgeB + (size_t)b * N_ * 128;
  uint4 lu = *(const uint4*)&lb[(size_t)(n0 + slot) * 128 + co * 8];
  float l[8]; unpack8(lu, l);
  float se[8] = {0,0,0,0,0,0,0,0}, se2[8] = {0,0,0,0,0,0,0,0};
#pragma unroll
  for (int r = 0; r < 2; r++) {
    uint4 eu[8];
#pragma unroll
    for (int k = 0; k < 8; k++)
      eu[k] = *(const uint4*)&eb[(size_t)knn_s[slot * 16 + r * 8 + k] * 128 + co * 8];
#pragma unroll
    for (int k = 0; k < 8; k++) {
      float e[8]; unpack8(eu[k], e);
#pragma unroll
      for (int j = 0; j < 8; j++) { se[j] += e[j]; se2[j] = fmaf(e[j], e[j], se2[j]); }
    }
  }
  // derive diff stats: sd = se - 16 l ; sd2 = se2 - 2 l se + 16 l^2
  float lS[8], lQ[8], dS[8], dQ[8];
#pragma unroll
  for (int j = 0; j < 8; j++) {
    lS[j] = l[j];
    lQ[j] = l[j] * l[j];
    dS[j] = se[j] - 16.f * l[j];
    dQ[j] = fmaf(-2.f * l[j], se[j], se2[j]) + 16.f * lQ[j];
  }
  // butterfly over the 4 slot-groups within the wave (xor 16, 32)
#pragma unroll
  for (int off = 16; off <= 32; off <<= 1) {
#pragma unroll
    for (int j = 0; j < 8; j++) {
      lS[j] += __shfl_xor(lS[j], off);
      lQ[j] += __shfl_xor(lQ[j], off);
      dS[j] += __shfl_xor(dS[j], off);
      dQ[j] += __shfl_xor(dQ[j], off);
    }
  }
  if ((t & 48) == 0) {              // one lane per co per wave
    int ch = co * 8;
#pragma unroll
    for (int j = 0; j < 8; j++) {
      atomicAdd(&red[ch + j], lS[j]);
      atomicAdd(&red[128 + ch + j], dS[j]);
      atomicAdd(&red[256 + ch + j], lQ[j]);
      atomicAdd(&red[384 + ch + j], dQ[j]);
    }
  }
  __syncthreads();
  float* pb = partials + (size_t)blockIdx.x * 512;
  pb[t] = red[t];
  pb[t + 256] = red[t + 256];
}

// K3: reduce partials -> per-channel affine coefs y = a*x + b.
__global__ __launch_bounds__(256) void k_coef(const float* __restrict__ partials,
    const float* __restrict__ gamma, const float* __restrict__ beta,
    float* __restrict__ coef) {
  const int c = blockIdx.x;
  const int t = threadIdx.x;
  float s = 0.f, q = 0.f;
  for (int j = t; j < NBLK_STATS; j += 256) {
    s += partials[(size_t)j * 512 + c];
    q += partials[(size_t)j * 512 + 256 + c];
  }
#pragma unroll
  for (int off = 32; off > 0; off >>= 1) {
    s += __shfl_down(s, off);
    q += __shfl_down(q, off);
  }
  __shared__ float rs[4], rq[4];
  int w = t >> 6;
  if ((t & 63) == 0) { rs[w] = s; rq[w] = q; }
  __syncthreads();
  if (t == 0) {
    float S = rs[0] + rs[1] + rs[2] + rs[3];
    float Q = rq[0] + rq[1] + rq[2] + rq[3];
    float cnt = (c < 128) ? (float)(B_ * N_) : (float)(B_ * N_ * K_);
    float mean = S / cnt;
    float var = fmaxf(Q / cnt - mean * mean, 0.f);
    float a = gamma[c] * rsqrtf(var + 1e-5f);
    coef[c] = a;
    coef[256 + c] = beta[c] - mean * a;
  }
}

// K4: output. 32 n/block; thread = (slot, octet) handling 2 n. Buffered gathers,
// folded affine, LDS transpose (stride 36) -> coalesced float4 stores.
__global__ __launch_bounds__(256, 4) void k_out(const unsigned short* __restrict__ localB,
    const unsigned short* __restrict__ edgeB, const int* __restrict__ knn,
    const float* __restrict__ coef, float* __restrict__ out) {
  __shared__ float tile[256][36];
  __shared__ int knn_s[512];
  const int t = threadIdx.x;
  const int b = blockIdx.x >> 8;
  const int n0 = (blockIdx.x & 255) << 5;
  const int* kb = knn + ((size_t)b * N_ + n0) * K_;
  knn_s[t] = kb[t];
  knn_s[t + 256] = kb[t + 256];
  __syncthreads();
  const int slot = t >> 4;
  const int co = t & 15;
  float caL[8], cbL[8], caE[8], cbE[8];
  *(float4*)&caL[0] = *(const float4*)&coef[co * 8];
  *(float4*)&caL[4] = *(const float4*)&coef[co * 8 + 4];
  *(float4*)&caE[0] = *(const float4*)&coef[128 + co * 8];
  *(float4*)&caE[4] = *(const float4*)&coef[128 + co * 8 + 4];
  *(float4*)&cbL[0] = *(const float4*)&coef[256 + co * 8];
  *(float4*)&cbL[4] = *(const float4*)&coef[256 + co * 8 + 4];
  *(float4*)&cbE[0] = *(const float4*)&coef[384 + co * 8];
  *(float4*)&cbE[4] = *(const float4*)&coef[384 + co * 8 + 4];
  const unsigned short* lb = localB + (size_t)b * N_ * 128;
  const unsigned short* eb = edgeB + (size_t)b * N_ * 128;
#pragma unroll
  for (int h = 0; h < 2; h++) {
    int nl = slot + h * 16;
    uint4 lu = *(const uint4*)&lb[(size_t)(n0 + nl) * 128 + co * 8];
    float l[8]; unpack8(lu, l);
    float hc[8];
#pragma unroll
    for (int j = 0; j < 8; j++) hc[j] = fmaf(-l[j], caE[j], cbE[j]);
    float acc[8] = {0,0,0,0,0,0,0,0};
#pragma unroll
    for (int r = 0; r < 2; r++) {
      uint4 eu[8];
#pragma unroll
      for (int k = 0; k < 8; k++)
        eu[k] = *(const uint4*)&eb[(size_t)knn_s[nl * 16 + r * 8 + k] * 128 + co * 8];
#pragma unroll
      for (int k = 0; k < 8; k++) {
        float e[8]; unpack8(eu[k], e);
#pragma unroll
        for (int j = 0; j < 8; j++)
          acc[j] += fmaxf(fmaf(e[j], caE[j], hc[j]), 0.f);
      }
    }
#pragma unroll
    for (int j = 0; j < 8; j++) {
      tile[co * 8 + j][nl] = fmaxf(fmaf(l[j], caL[j], cbL[j]), 0.f);
      tile[128 + co * 8 + j][nl] = acc[j] * 0.0625f;
    }
  }
  __syncthreads();
  float* ob = out + (size_t)b * 256 * N_;
  const int cr = t >> 3;
  const int n4 = (t & 7) << 2;
#pragma unroll
  for (int p = 0; p < 8; p++) {
    int c = (p << 5) + cr;
    float4 v = *(float4*)&tile[c][n4];
    *(float4*)&ob[(size_t)c * N_ + n0 + n4] = v;
  }
}

extern "C" void kernel_launch(void* const* d_in, const int* in_sizes, int n_in,
                              void* d_out, int out_size, void* d_ws, size_t ws_size,
                              hipStream_t stream) {
  const float* feat  = (const float*)d_in[0];
  const int*   knn   = (const int*)d_in[1];
  const float* w1    = (const float*)d_in[2];
  const float* w2    = (const float*)d_in[3];
  const float* gamma = (const float*)d_in[4];
  const float* beta  = (const float*)d_in[5];
  if (ws_size < WS_BYTES) return;
  unsigned char* ws = (unsigned char*)d_ws;
  unsigned short* localB = (unsigned short*)(ws + OFF_LOCAL);
  unsigned short* edgeB  = (unsigned short*)(ws + OFF_EDGE);
  unsigned short* wbf1   = (unsigned short*)(ws + OFF_WBF1);
  unsigned short* wbf2   = (unsigned short*)(ws + OFF_WBF2);
  float* partials        = (float*)(ws + OFF_PART);
  float* coef            = (float*)(ws + OFF_COEF);
  float* outp = (float*)d_out;

  hipLaunchKernelGGL(k_prep, dim3(64), dim3(256), 0, stream, w1, w2, wbf1, wbf2);
  hipLaunchKernelGGL(k_gemm, dim3(512), dim3(256), 0, stream, feat, wbf1, wbf2, localB, edgeB);
  hipLaunchKernelGGL(k_stats, dim3(2048), dim3(256), 0, stream, localB, edgeB, knn, partials);
  hipLaunchKernelGGL(k_coef, dim3(256), dim3(256), 0, stream, partials, gamma, beta, coef);
  hipLaunchKernelGGL(k_out, dim3(1024), dim3(256), 0, stream, localB, edgeB, knn, coef, outp);
}

// Round 4
// 156.374 us; speedup vs baseline: 1.2630x; 1.0180x over previous
//
#include <hip/hip_runtime.h>
#include <hip/hip_bf16.h>

#define B_ 4
#define C_ 128
#define N_ 8192
#define K_ 16
#define NBLK_STATS 2048

typedef __attribute__((ext_vector_type(8))) short short8;
typedef __attribute__((ext_vector_type(4))) float floatx4;

static __device__ __forceinline__ unsigned short f2b(float x) {
  return __builtin_bit_cast(unsigned short, __float2bfloat16(x));
}
// unpack 8 bf16 (uint4) -> 8 floats.
static __device__ __forceinline__ void unpack8(uint4 u, float* f) {
  const unsigned* w = (const unsigned*)&u;
#pragma unroll
  for (int i = 0; i < 4; i++) {
    f[2 * i]     = __builtin_bit_cast(float, w[i] << 16);
    f[2 * i + 1] = __builtin_bit_cast(float, w[i] & 0xffff0000u);
  }
}

// workspace byte offsets
#define OFF_LOCAL 0ULL
#define OFF_EDGE  8388608ULL
#define OFF_WBF1  16777216ULL
#define OFF_WBF2  16809984ULL
#define OFF_PART  16842752ULL
#define OFF_COEF  21037056ULL
#define WS_BYTES  21039104ULL

// K0: cast W1,W2 -> bf16, same [o][c] layout.
__global__ __launch_bounds__(256) void k_prep(const float* __restrict__ w1,
    const float* __restrict__ w2, unsigned short* __restrict__ wbf1,
    unsigned short* __restrict__ wbf2) {
  int i = blockIdx.x * 256 + threadIdx.x;
  wbf1[i] = f2b(w1[i]);
  wbf2[i] = f2b(w2[i]);
}

// XCD-affine swizzle: batch b lives on XCDs {2b, 2b+1} (blockIdx%8 round-robin).
// chunkbits = log2(chunks per batch).
static __device__ __forceinline__ void swz(int bid, int& b, int& chunk) {
  b = (bid & 7) >> 1;
  chunk = ((bid >> 3) << 1) | (bid & 1);
}

// K1: MFMA dual-GEMM, output (b,n,o) bf16. 512 blocks, 128 chunks of 64 n per batch.
__global__ __launch_bounds__(256) void k_gemm(const float* __restrict__ feat,
    const unsigned short* __restrict__ wbf1, const unsigned short* __restrict__ wbf2,
    unsigned short* __restrict__ localB, unsigned short* __restrict__ edgeB) {
  __shared__ __align__(16) unsigned short lds_u[128 * 68];
  const int t = threadIdx.x;
  int b, chunk; swz(blockIdx.x, b, chunk);
  const int n0 = chunk << 6;
  const float* fb = feat + (size_t)b * C_ * N_;
#pragma unroll
  for (int i = 0; i < 8; i++) {
    int c = i * 16 + (t >> 4);
    int n4 = (t & 15) << 2;
    floatx4 f = __builtin_nontemporal_load((const floatx4*)&fb[(size_t)c * N_ + n0 + n4]);
    ushort4 u = make_ushort4(f2b(f[0]), f2b(f[1]), f2b(f[2]), f2b(f[3]));
    *(ushort4*)&lds_u[c * 68 + n4] = u;
  }
  __syncthreads();
  const int lane = t & 63, wv = t >> 6, l15 = lane & 15, q = lane >> 4;
  short8 bfrag[4];
#pragma unroll
  for (int ks = 0; ks < 4; ks++)
#pragma unroll
    for (int j = 0; j < 8; j++)
      bfrag[ks][j] = (short)lds_u[(ks * 32 + q * 8 + j) * 68 + wv * 16 + l15];
  __syncthreads();

#pragma unroll 1
  for (int g = 0; g < 2; g++) {
    const unsigned short* Wg = g ? wbf2 : wbf1;
    floatx4 acc[8];
#pragma unroll
    for (int mt = 0; mt < 8; mt++) acc[mt] = (floatx4){0.f, 0.f, 0.f, 0.f};
#pragma unroll
    for (int ks = 0; ks < 4; ks++) {
      short8 af[8];
#pragma unroll
      for (int mt = 0; mt < 8; mt++)
        af[mt] = *(const short8*)(Wg + (size_t)(mt * 16 + l15) * 128 + ks * 32 + q * 8);
#pragma unroll
      for (int mt = 0; mt < 8; mt++)
        acc[mt] = __builtin_amdgcn_mfma_f32_16x16x32_bf16(af[mt], bfrag[ks], acc[mt], 0, 0, 0);
    }
#pragma unroll
    for (int mt = 0; mt < 8; mt++) {
      ushort4 u = make_ushort4(f2b(acc[mt][0]), f2b(acc[mt][1]), f2b(acc[mt][2]), f2b(acc[mt][3]));
      *(ushort4*)&lds_u[(wv * 16 + l15) * 136 + mt * 16 + q * 4] = u;
    }
    __syncthreads();
    unsigned short* dst = (g ? edgeB : localB) + ((size_t)b * N_ + n0) * 128;
#pragma unroll
    for (int i = 0; i < 4; i++) {
      int ng = i * 16 + (t >> 4);
      float4 v = *(float4*)&lds_u[ng * 136 + (t & 15) * 8];
      *(float4*)&dst[(size_t)ng * 128 + (t & 15) * 8] = v;
    }
    __syncthreads();
  }
}

// K2: stats. 2048 blocks, 512 chunks of 16 n per batch. All 16 neighbors in flight.
__global__ __launch_bounds__(256, 4) void k_stats(const unsigned short* __restrict__ localB,
    const unsigned short* __restrict__ edgeB, const int* __restrict__ knn,
    float* __restrict__ partials) {
  __shared__ int knn_s[256];
  __shared__ float red[512];
  const int t = threadIdx.x;
  int b, chunk; swz(blockIdx.x, b, chunk);
  const int n0 = chunk << 4;
  red[t] = 0.f; red[t + 256] = 0.f;
  knn_s[t] = knn[((size_t)b * N_ + n0) * K_ + t];
  __syncthreads();
  const int slot = t >> 4;          // n = n0 + slot
  const int co = t & 15;            // channels co*8 .. co*8+7
  const unsigned short* lb = localB + (size_t)b * N_ * 128;
  const unsigned short* eb = edgeB + (size_t)b * N_ * 128;
  uint4 lu = *(const uint4*)&lb[(size_t)(n0 + slot) * 128 + co * 8];
  float l[8]; unpack8(lu, l);
  uint4 eu[16];
#pragma unroll
  for (int k = 0; k < 16; k++)
    eu[k] = *(const uint4*)&eb[(size_t)knn_s[slot * 16 + k] * 128 + co * 8];
  float se[8] = {0,0,0,0,0,0,0,0}, se2[8] = {0,0,0,0,0,0,0,0};
#pragma unroll
  for (int k = 0; k < 16; k++) {
    float e[8]; unpack8(eu[k], e);
#pragma unroll
    for (int j = 0; j < 8; j++) { se[j] += e[j]; se2[j] = fmaf(e[j], e[j], se2[j]); }
  }
  float lS[8], lQ[8], dS[8], dQ[8];
#pragma unroll
  for (int j = 0; j < 8; j++) {
    lS[j] = l[j];
    lQ[j] = l[j] * l[j];
    dS[j] = se[j] - 16.f * l[j];
    dQ[j] = fmaf(-2.f * l[j], se[j], se2[j]) + 16.f * lQ[j];
  }
#pragma unroll
  for (int off = 16; off <= 32; off <<= 1) {
#pragma unroll
    for (int j = 0; j < 8; j++) {
      lS[j] += __shfl_xor(lS[j], off);
      lQ[j] += __shfl_xor(lQ[j], off);
      dS[j] += __shfl_xor(dS[j], off);
      dQ[j] += __shfl_xor(dQ[j], off);
    }
  }
  if ((t & 48) == 0) {
    int ch = co * 8;
#pragma unroll
    for (int j = 0; j < 8; j++) {
      atomicAdd(&red[ch + j], lS[j]);
      atomicAdd(&red[128 + ch + j], dS[j]);
      atomicAdd(&red[256 + ch + j], lQ[j]);
      atomicAdd(&red[384 + ch + j], dQ[j]);
    }
  }
  __syncthreads();
  float* pb = partials + (size_t)blockIdx.x * 512;
  pb[t] = red[t];
  pb[t + 256] = red[t + 256];
}

// K3: reduce partials -> per-channel affine coefs y = a*x + b.
__global__ __launch_bounds__(256) void k_coef(const float* __restrict__ partials,
    const float* __restrict__ gamma, const float* __restrict__ beta,
    float* __restrict__ coef) {
  const int c = blockIdx.x;
  const int t = threadIdx.x;
  float s = 0.f, q = 0.f;
  for (int j = t; j < NBLK_STATS; j += 256) {
    s += partials[(size_t)j * 512 + c];
    q += partials[(size_t)j * 512 + 256 + c];
  }
#pragma unroll
  for (int off = 32; off > 0; off >>= 1) {
    s += __shfl_down(s, off);
    q += __shfl_down(q, off);
  }
  __shared__ float rs[4], rq[4];
  int w = t >> 6;
  if ((t & 63) == 0) { rs[w] = s; rq[w] = q; }
  __syncthreads();
  if (t == 0) {
    float S = rs[0] + rs[1] + rs[2] + rs[3];
    float Q = rq[0] + rq[1] + rq[2] + rq[3];
    float cnt = (c < 128) ? (float)(B_ * N_) : (float)(B_ * N_ * K_);
    float mean = S / cnt;
    float var = fmaxf(Q / cnt - mean * mean, 0.f);
    float a = gamma[c] * rsqrtf(var + 1e-5f);
    coef[c] = a;
    coef[256 + c] = beta[c] - mean * a;
  }
}

// K4: output. 1024 blocks, 256 chunks of 32 n per batch. Non-temporal final stores.
__global__ __launch_bounds__(256, 4) void k_out(const unsigned short* __restrict__ localB,
    const unsigned short* __restrict__ edgeB, const int* __restrict__ knn,
    const float* __restrict__ coef, float* __restrict__ out) {
  __shared__ float tile[256][36];
  __shared__ int knn_s[512];
  const int t = threadIdx.x;
  int b, chunk; swz(blockIdx.x, b, chunk);
  const int n0 = chunk << 5;
  const int* kb = knn + ((size_t)b * N_ + n0) * K_;
  knn_s[t] = kb[t];
  knn_s[t + 256] = kb[t + 256];
  __syncthreads();
  const int slot = t >> 4;
  const int co = t & 15;
  float caL[8], cbL[8], caE[8], cbE[8];
  *(float4*)&caL[0] = *(const float4*)&coef[co * 8];
  *(float4*)&caL[4] = *(const float4*)&coef[co * 8 + 4];
  *(float4*)&caE[0] = *(const float4*)&coef[128 + co * 8];
  *(float4*)&caE[4] = *(const float4*)&coef[128 + co * 8 + 4];
  *(float4*)&cbL[0] = *(const float4*)&coef[256 + co * 8];
  *(float4*)&cbL[4] = *(const float4*)&coef[256 + co * 8 + 4];
  *(float4*)&cbE[0] = *(const float4*)&coef[384 + co * 8];
  *(float4*)&cbE[4] = *(const float4*)&coef[384 + co * 8 + 4];
  const unsigned short* lb = localB + (size_t)b * N_ * 128;
  const unsigned short* eb = edgeB + (size_t)b * N_ * 128;
#pragma unroll
  for (int h = 0; h < 2; h++) {
    int nl = slot + h * 16;
    uint4 lu = *(const uint4*)&lb[(size_t)(n0 + nl) * 128 + co * 8];
    float l[8]; unpack8(lu, l);
    float hc[8];
#pragma unroll
    for (int j = 0; j < 8; j++) hc[j] = fmaf(-l[j], caE[j], cbE[j]);
    float acc[8] = {0,0,0,0,0,0,0,0};
#pragma unroll
    for (int r = 0; r < 2; r++) {
      uint4 eu[8];
#pragma unroll
      for (int k = 0; k < 8; k++)
        eu[k] = *(const uint4*)&eb[(size_t)knn_s[nl * 16 + r * 8 + k] * 128 + co * 8];
#pragma unroll
      for (int k = 0; k < 8; k++) {
        float e[8]; unpack8(eu[k], e);
#pragma unroll
        for (int j = 0; j < 8; j++)
          acc[j] += fmaxf(fmaf(e[j], caE[j], hc[j]), 0.f);
      }
    }
#pragma unroll
    for (int j = 0; j < 8; j++) {
      tile[co * 8 + j][nl] = fmaxf(fmaf(l[j], caL[j], cbL[j]), 0.f);
      tile[128 + co * 8 + j][nl] = acc[j] * 0.0625f;
    }
  }
  __syncthreads();
  float* ob = out + (size_t)b * 256 * N_;
  const int cr = t >> 3;
  const int n4 = (t & 7) << 2;
#pragma unroll
  for (int p = 0; p < 8; p++) {
    int c = (p << 5) + cr;
    floatx4 v = *(floatx4*)&tile[c][n4];
    __builtin_nontemporal_store(v, (floatx4*)&ob[(size_t)c * N_ + n0 + n4]);
  }
}

extern "C" void kernel_launch(void* const* d_in, const int* in_sizes, int n_in,
                              void* d_out, int out_size, void* d_ws, size_t ws_size,
                              hipStream_t stream) {
  const float* feat  = (const float*)d_in[0];
  const int*   knn   = (const int*)d_in[1];
  const float* w1    = (const float*)d_in[2];
  const float* w2    = (const float*)d_in[3];
  const float* gamma = (const float*)d_in[4];
  const float* beta  = (const float*)d_in[5];
  if (ws_size < WS_BYTES) return;
  unsigned char* ws = (unsigned char*)d_ws;
  unsigned short* localB = (unsigned short*)(ws + OFF_LOCAL);
  unsigned short* edgeB  = (unsigned short*)(ws + OFF_EDGE);
  unsigned short* wbf1   = (unsigned short*)(ws + OFF_WBF1);
  unsigned short* wbf2   = (unsigned short*)(ws + OFF_WBF2);
  float* partials        = (float*)(ws + OFF_PART);
  float* coef            = (float*)(ws + OFF_COEF);
  float* outp = (float*)d_out;

  hipLaunchKernelGGL(k_prep, dim3(64), dim3(256), 0, stream, w1, w2, wbf1, wbf2);
  hipLaunchKernelGGL(k_gemm, dim3(512), dim3(256), 0, stream, feat, wbf1, wbf2, localB, edgeB);
  hipLaunchKernelGGL(k_stats, dim3(2048), dim3(256), 0, stream, localB, edgeB, knn, partials);
  hipLaunchKernelGGL(k_coef, dim3(256), dim3(256), 0, stream, partials, gamma, beta, coef);
  hipLaunchKernelGGL(k_out, dim3(1024), dim3(256), 0, stream, localB, edgeB, knn, coef, outp);
}